// Round 1
// baseline (54062.592 us; speedup 1.0000x reference)
//
#include <hip/hip_runtime.h>
#include <hip/hip_cooperative_groups.h>

namespace cg = cooperative_groups;

// Shapes: VOCAB=128, EMBED=512, HIDDEN=1024, B=64, T=512. All inputs fp32, x int32.
// ws layout (bytes):
//   table0T : [4096 cols][128 vocab] fp32           @ 0         (2 MB)
//   fcwT    : [1024 k][128 v] fp32                  @ 2097152   (512 KB)
//   hTA     : [2 bufs][512 kp][64 b][2] fp16        @ 2621440   (256 KB)
//   hTB     : [2 bufs][512 kp][64 b][2] fp16        @ 2883584   (256 KB)
//   h2s     : [512 t][512 kp][64 b][2] fp16         @ 3145728   (64 MB)

typedef _Float16 h2v __attribute__((ext_vector_type(2)));
typedef _Float16 h8v __attribute__((ext_vector_type(8)));

__device__ __forceinline__ h2v mk2(_Float16 a, _Float16 b) {
  h2v r; r.x = a; r.y = b; return r;
}

__device__ __forceinline__ float fdot2_(h2v a, h2v b, float c) {
#if __has_builtin(__builtin_amdgcn_fdot2)
  return __builtin_amdgcn_fdot2(a, b, c, false);
#else
  return c + (float)a.x * (float)b.x + (float)a.y * (float)b.y;
#endif
}

__device__ __forceinline__ float sigf(float x) {
  return 1.0f / (1.0f + __expf(-x));
}

// ---------------------------------------------------------------- prep ----
// blocks [0,2048): table0T[col][v] = emb[v]·w_ih0[col] + b_ih0[col] + b_hh0[col]
// blocks [2048,2560): fcwT[k][v] = fc_w[v][k]
// blocks [2560,2624): zero hTA + hTB (both ping-pong buffers)
__global__ __launch_bounds__(256) void prep_kernel(
    const float* __restrict__ emb, const float* __restrict__ w_ih0,
    const float* __restrict__ b_ih0, const float* __restrict__ b_hh0,
    const float* __restrict__ fc_w, float* __restrict__ table0T,
    float* __restrict__ fcwT, unsigned* __restrict__ zbuf) {
  const int blk = blockIdx.x, tid = threadIdx.x;
  if (blk < 2048) {
    const int col = blk * 2 + (tid >> 7);
    const int v = tid & 127;
    float acc = b_ih0[col] + b_hh0[col];
    const float* er = emb + v * 512;
    const float* wr = w_ih0 + col * 512;
#pragma unroll 4
    for (int k = 0; k < 512; ++k) acc = fmaf(er[k], wr[k], acc);
    table0T[col * 128 + v] = acc;
  } else if (blk < 2560) {
    const int idx = (blk - 2048) * 256 + tid;   // [0, 131072)
    const int v = idx & 127, k = idx >> 7;
    fcwT[k * 128 + v] = fc_w[v * 1024 + k];
  } else {
    const int idx = (blk - 2560) * 256 + tid;   // [0, 16384)
#pragma unroll
    for (int q = 0; q < 8; ++q) zbuf[idx * 8 + q] = 0u;
  }
}

// ------------------------------------------------------------ recurrent ----
// One K=1024 GEMM slice: 2 gate-columns for (b, unit). h is [512 kp][64 b]
// fp16-pairs (coalesced, lane=b); W rows are LDS, broadcast across the wave.
__device__ __forceinline__ void gemm_part(const _Float16* __restrict__ hbuf,
                                          const _Float16* __restrict__ w0p,
                                          const _Float16* __restrict__ w1p,
                                          int b, float& a0, float& a1) {
  const h2v* __restrict__ hp = (const h2v*)hbuf;      // [512][64]
  const h8v* __restrict__ w0 = (const h8v*)w0p;       // 128 groups of 8 k
  const h8v* __restrict__ w1 = (const h8v*)w1p;
#pragma unroll 2
  for (int kg = 0; kg < 128; ++kg) {
    const h8v w0v = w0[kg];
    const h8v w1v = w1[kg];
    const h2v* hh = hp + kg * 256 + b;                // (kg*4+q)*64 + b
    const h2v q0 = hh[0], q1 = hh[64], q2 = hh[128], q3 = hh[192];
    a0 = fdot2_(q0, mk2(w0v[0], w0v[1]), a0);
    a0 = fdot2_(q1, mk2(w0v[2], w0v[3]), a0);
    a0 = fdot2_(q2, mk2(w0v[4], w0v[5]), a0);
    a0 = fdot2_(q3, mk2(w0v[6], w0v[7]), a0);
    a1 = fdot2_(q0, mk2(w1v[0], w1v[1]), a1);
    a1 = fdot2_(q1, mk2(w1v[2], w1v[3]), a1);
    a1 = fdot2_(q2, mk2(w1v[4], w1v[5]), a1);
    a1 = fdot2_(q3, mk2(w1v[6], w1v[7]), a1);
  }
}

// Cooperative kernel: 512 blocks x 256 threads. Block owns units u0=2*blk,
// u0+1 (8 gate-rows of each weight matrix, LDS-resident fp16 for all steps).
// Thread = (b = tid&63, j = unit bit, p = gate-pair bit). Skewed pipeline:
// iteration it does layer0 step t=it and layer1 step t-1 -> one grid.sync.
__global__ __launch_bounds__(256, 2) void lstm_coop(
    const int* __restrict__ x, const float* __restrict__ table0T,
    const float* __restrict__ w_hh0, const float* __restrict__ w_ih1,
    const float* __restrict__ w_hh1, const float* __restrict__ b_ih1,
    const float* __restrict__ b_hh1, _Float16* __restrict__ hTA,
    _Float16* __restrict__ hTB, _Float16* __restrict__ h2s) {
  __shared__ _Float16 WL0[8][1024];   // w_hh0 slice, [j*4+g][k], 16 KB
  __shared__ _Float16 WLa[8][1024];   // w_ih1 slice
  __shared__ _Float16 WLb[8][1024];   // w_hh1 slice
  __shared__ float zx[256][2];        // gate-pair exchange

  const int tid = threadIdx.x, blk = blockIdx.x;
  const int b = tid & 63, s = tid >> 6;
  const int j = s & 1;                // unit within block
  const int p = s >> 1;               // gate pair: 0 -> (i,f), 1 -> (g,o)
  const int g0 = 2 * p, g1 = 2 * p + 1;
  const int u0 = blk * 2;
  const int u = u0 + j;

  // Stage the block's 8 rows of each weight matrix into LDS (fp32 -> fp16),
  // coalesced; done once, reused for all 512 timesteps.
  {
    const float* mats[3] = {w_hh0, w_ih1, w_hh1};
    _Float16* dsts[3] = {&WL0[0][0], &WLa[0][0], &WLb[0][0]};
    for (int m = 0; m < 3; ++m)
      for (int r = 0; r < 8; ++r) {          // r = jj*4 + gg
        const int jj = r >> 2, gg = r & 3;
        const float* src = mats[m] + (gg * 1024 + u0 + jj) * 1024;
        _Float16* dst = dsts[m] + r * 1024;
        for (int k = tid; k < 1024; k += 256) dst[k] = (_Float16)src[k];
      }
  }
  __syncthreads();

  const _Float16* w00 = &WL0[j * 4 + g0][0];
  const _Float16* w01 = &WL0[j * 4 + g1][0];
  const _Float16* wa0 = &WLa[j * 4 + g0][0];
  const _Float16* wa1 = &WLa[j * 4 + g1][0];
  const _Float16* wb0 = &WLb[j * 4 + g0][0];
  const _Float16* wb1 = &WLb[j * 4 + g1][0];

  const int c0i = g0 * 1024 + u, c1i = g1 * 1024 + u;
  const float bias0 = b_ih1[c0i] + b_hh1[c0i];
  const float bias1 = b_ih1[c1i] + b_hh1[c1i];
  const int t0base0 = c0i * 128, t0base1 = c1i * 128;

  cg::grid_group grid = cg::this_grid();
  float cA = 0.0f, cB = 0.0f;         // cell states, register-resident

  for (int it = 0; it <= 512; ++it) {
    const _Float16* hA_r = hTA + (it & 1) * 65536;
    _Float16* hA_w = hTA + ((it + 1) & 1) * 65536;
    const _Float16* hB_r = hTB + (it & 1) * 65536;
    _Float16* hB_w = hTB + ((it + 1) & 1) * 65536;

    float a0 = 0.0f, a1 = 0.0f, a2 = 0.0f, a3 = 0.0f;
    if (it < 512) {                    // layer 0, step t = it
      const int xv = x[b * 512 + it];
      a0 = table0T[t0base0 + xv];      // xin0 via vocab table gather
      a1 = table0T[t0base1 + xv];
      gemm_part(hA_r, w00, w01, b, a0, a1);
    }
    if (it >= 1) {                     // layer 1, step t = it-1
      a2 = bias0;
      a3 = bias1;
      gemm_part(hA_r, wa0, wa1, b, a2, a3);   // input contribution (h1_{t})
      gemm_part(hB_r, wb0, wb1, b, a2, a3);   // recurrent (h2_{t-1})
    }

    // Exchange gate pairs: (i,f) threads (tid<128) collect (g,o) from partner.
    zx[tid][0] = a0; zx[tid][1] = a1;
    __syncthreads();
    float zg0 = 0.0f, zo0 = 0.0f;
    if (tid < 128) { zg0 = zx[tid + 128][0]; zo0 = zx[tid + 128][1]; }
    __syncthreads();
    zx[tid][0] = a2; zx[tid][1] = a3;
    __syncthreads();

    if (tid < 128) {
      if (it < 512) {
        const float ig = sigf(a0), fg = sigf(a1);
        const float gg = tanhf(zg0), og = sigf(zo0);
        cA = fg * cA + ig * gg;
        hA_w[blk * 128 + b * 2 + j] = (_Float16)(og * tanhf(cA));
      }
      if (it >= 1) {
        const float zg1 = zx[tid + 128][0], zo1 = zx[tid + 128][1];
        const float ig = sigf(a2), fg = sigf(a3);
        const float gg = tanhf(zg1), og = sigf(zo1);
        cB = fg * cB + ig * gg;
        const float hv = og * tanhf(cB);
        hB_w[blk * 128 + b * 2 + j] = (_Float16)hv;
        h2s[(it - 1) * 65536 + blk * 128 + b * 2 + j] = (_Float16)hv;
      }
    }
    grid.sync();
  }
}

// ---------------------------------------------------------------- FC ----
// out[b][t][v] = sum_u h2[b][t][u] * fc_w[v][u] + fc_b[v]
// grid = 512 t * 4 b-slices; block stages h2 slice [16 b][1024 k] in LDS.
__global__ __launch_bounds__(256, 2) void fc_kernel(
    const _Float16* __restrict__ h2s, const float* __restrict__ fcwT,
    const float* __restrict__ fc_b, float* __restrict__ out) {
  __shared__ float hl[16][1024];      // 64 KB
  const int tid = threadIdx.x;
  const int t = blockIdx.x >> 2, bs = blockIdx.x & 3;
  const int v = tid & 127, hh = tid >> 7;

  const h2v* hp = (const h2v*)h2s;
  for (int idx = tid; idx < 8192; idx += 256) {
    const int kp = idx >> 4, bl = idx & 15;
    const h2v pr = hp[(t * 512 + kp) * 64 + bs * 16 + bl];
    hl[bl][2 * kp] = (float)pr.x;
    hl[bl][2 * kp + 1] = (float)pr.y;
  }
  __syncthreads();

  float acc[8];
#pragma unroll
  for (int i = 0; i < 8; ++i) acc[i] = 0.0f;
  const int bl0 = hh * 8;
#pragma unroll 1
  for (int k4 = 0; k4 < 256; ++k4) {
    const int k = k4 * 4;
    const float w0 = fcwT[(k + 0) * 128 + v];
    const float w1 = fcwT[(k + 1) * 128 + v];
    const float w2 = fcwT[(k + 2) * 128 + v];
    const float w3 = fcwT[(k + 3) * 128 + v];
#pragma unroll
    for (int i = 0; i < 8; ++i) {
      const float4 hv = *(const float4*)&hl[bl0 + i][k];
      acc[i] += hv.x * w0 + hv.y * w1 + hv.z * w2 + hv.w * w3;
    }
  }
  const float bias = fc_b[v];
#pragma unroll
  for (int i = 0; i < 8; ++i) {
    const int bb = bs * 16 + bl0 + i;
    out[(bb * 512 + t) * 128 + v] = acc[i] + bias;
  }
}

// ------------------------------------------------------------- launch ----
extern "C" void kernel_launch(void* const* d_in, const int* in_sizes, int n_in,
                              void* d_out, int out_size, void* d_ws,
                              size_t ws_size, hipStream_t stream) {
  const int* x = (const int*)d_in[0];
  const float* emb = (const float*)d_in[1];
  const float* w_ih0 = (const float*)d_in[2];
  const float* w_hh0 = (const float*)d_in[3];
  const float* b_ih0 = (const float*)d_in[4];
  const float* b_hh0 = (const float*)d_in[5];
  const float* w_ih1 = (const float*)d_in[6];
  const float* w_hh1 = (const float*)d_in[7];
  const float* b_ih1 = (const float*)d_in[8];
  const float* b_hh1 = (const float*)d_in[9];
  const float* fc_w = (const float*)d_in[10];
  const float* fc_b = (const float*)d_in[11];
  float* out = (float*)d_out;

  char* ws = (char*)d_ws;
  float* table0T = (float*)(ws);
  float* fcwT = (float*)(ws + 2097152);
  _Float16* hTA = (_Float16*)(ws + 2621440);
  _Float16* hTB = (_Float16*)(ws + 2883584);
  _Float16* h2s = (_Float16*)(ws + 3145728);
  unsigned* zb = (unsigned*)(ws + 2621440);

  prep_kernel<<<2624, 256, 0, stream>>>(emb, w_ih0, b_ih0, b_hh0, fc_w,
                                        table0T, fcwT, zb);

  const float* table0Tc = table0T;
  _Float16* hTAa = hTA;
  _Float16* hTBa = hTB;
  _Float16* h2sa = h2s;
  void* args[] = {(void*)&x,     (void*)&table0Tc, (void*)&w_hh0,
                  (void*)&w_ih1, (void*)&w_hh1,    (void*)&b_ih1,
                  (void*)&b_hh1, (void*)&hTAa,     (void*)&hTBa,
                  (void*)&h2sa};
  hipLaunchCooperativeKernel(lstm_coop, dim3(512), dim3(256), args, 0, stream);

  fc_kernel<<<2048, 256, 0, stream>>>(h2s, fcwT, fc_b, out);
}

// Round 2
// 22225.475 us; speedup vs baseline: 2.4325x; 2.4325x over previous
//
#include <hip/hip_runtime.h>
#include <hip/hip_cooperative_groups.h>

namespace cg = cooperative_groups;

// Shapes: VOCAB=128, EMBED=512, HIDDEN=1024, B=64, T=512. Inputs fp32, x int32.
// ws layout (bytes):
//   tableV : [128 vocab][4096 C] fp32   @ 0         (2 MB)   xin0+bias, block-local col order
//   fcwT   : [1024 k][128 v] fp32       @ 2097152   (512 KB)
//   hcat   : [2 bufs][64 b][2048 k] f16 @ 2621440   (512 KB) k<1024: h1, k>=1024: h2
//   h2s    : [512 t][64 b][1024 u] f16  @ 3145728   (64 MB)
//
// Column mapping: global col C = blk*16 + g*4 + j  <->  gate-row g*1024 + blk*4 + j.

typedef _Float16 v8h __attribute__((ext_vector_type(8)));
typedef float v4f __attribute__((ext_vector_type(4)));
typedef _Float16 h2v __attribute__((ext_vector_type(2)));

__device__ __forceinline__ float sigf(float x) {
  return 1.0f / (1.0f + __expf(-x));
}

// ---------------------------------------------------------------- prep ----
__global__ __launch_bounds__(256) void prep_kernel(
    const float* __restrict__ emb, const float* __restrict__ w_ih0,
    const float* __restrict__ b_ih0, const float* __restrict__ b_hh0,
    const float* __restrict__ fc_w, float* __restrict__ tableV,
    float* __restrict__ fcwT, unsigned* __restrict__ zbuf) {
  const int blk = blockIdx.x, tid = threadIdx.x;
  if (blk < 2048) {
    // tableV[v][C] = emb[v]·w_ih0[row(C)] + b_ih0[row] + b_hh0[row]
    const int C = blk * 2 + (tid >> 7);
    const int v = tid & 127;
    const int row = ((C >> 2) & 3) * 1024 + (C >> 4) * 4 + (C & 3);
    float acc = b_ih0[row] + b_hh0[row];
    const float* er = emb + v * 512;
    const float* wr = w_ih0 + row * 512;
#pragma unroll 4
    for (int k = 0; k < 512; ++k) acc = fmaf(er[k], wr[k], acc);
    tableV[v * 4096 + C] = acc;
  } else if (blk < 2560) {
    const int idx = (blk - 2048) * 256 + tid;   // [0, 131072)
    const int v = idx & 127, k = idx >> 7;
    fcwT[k * 128 + v] = fc_w[v * 1024 + k];
  } else {
    // zero hcat (both ping-pong buffers): 131072 dwords over 32 blocks
    const int idx = (blk - 2560) * 256 + tid;
#pragma unroll
    for (int q = 0; q < 16; ++q) zbuf[idx * 16 + q] = 0u;
  }
}

// ------------------------------------------------------------ recurrent ----
// 256 blocks x 768 threads (12 waves, 1 block/CU). Block owns units
// u0=4*blk..u0+3 (16 gate-cols per layer). Weights LDS-resident fp16 in
// B-fragment-friendly [col][k] layout (+8 halfs pad -> 2-way-only conflicts).
// Skew: iteration it does layer0 step t=it (waves 0-3, M-tile each) and
// layer1 step t=it-1 (waves 4-11: (M-tile q, K-half s), LDS-reduced).
__global__ __launch_bounds__(768, 1) void lstm_mfma(
    const int* __restrict__ x, const float* __restrict__ tableV,
    const float* __restrict__ w_hh0, const float* __restrict__ w_ih1,
    const float* __restrict__ w_hh1, const float* __restrict__ b_ih1,
    const float* __restrict__ b_hh1, _Float16* __restrict__ hcat,
    _Float16* __restrict__ h2s) {
  __shared__ _Float16 W0L[16][1024 + 8];   // 33 KB
  __shared__ _Float16 W1L[16][2048 + 8];   // 66 KB (k<1024: w_ih1, else w_hh1)
  __shared__ float zs[12][16][17];         // per-wave C-tile scratch, 13 KB

  const int tid = threadIdx.x, blk = blockIdx.x;
  const int w = tid >> 6, l = tid & 63;
  const int lane16 = l & 15, quad = l >> 4;
  const int u0 = blk * 4;

  // --- stage weights (once): fp32 global -> fp16 LDS ---
  for (int e = tid; e < 16 * 1024; e += 768) {
    const int n = e >> 10, k = e & 1023;
    const int row = (n >> 2) * 1024 + u0 + (n & 3);
    W0L[n][k] = (_Float16)w_hh0[row * 1024 + k];
  }
  for (int e = tid; e < 16 * 2048; e += 768) {
    const int n = e >> 11, k = e & 2047;
    const int row = (n >> 2) * 1024 + u0 + (n & 3);
    const float src = (k < 1024) ? w_ih1[row * 1024 + k]
                                 : w_hh1[row * 1024 + (k - 1024)];
    W1L[n][k] = (_Float16)src;
  }

  // layer1 bias (folded into acc init of K-half s==0 waves); per-lane scalar.
  float bias1 = 0.0f;
  if (w >= 4 && ((w - 4) & 1) == 0) {
    const int row = (lane16 >> 2) * 1024 + u0 + (lane16 & 3);
    bias1 = b_ih1[row] + b_hh1[row];
  }
  __syncthreads();

  cg::grid_group grid = cg::this_grid();
  float cst = 0.0f;                        // cell state (per owner lane)
  const int eb = l >> 2, ej = l & 3;       // elementwise cell mapping

  for (int it = 0; it <= 512; ++it) {
    const _Float16* hr = hcat + (it & 1) * 131072;      // [64][2048]
    _Float16* hw = hcat + ((it + 1) & 1) * 131072;

    v4f acc = {0.0f, 0.0f, 0.0f, 0.0f};
    if (w < 4) {
      if (it < 512) {                      // layer 0, t = it
#pragma unroll
        for (int r = 0; r < 4; ++r) {
          const int b = w * 16 + quad * 4 + r;
          const int xv = x[b * 512 + it];
          acc[r] = tableV[xv * 4096 + blk * 16 + lane16];
        }
        const _Float16* ap = hr + (w * 16 + lane16) * 2048 + quad * 8;
        const _Float16* bp = &W0L[lane16][quad * 8];
#pragma unroll 8
        for (int kk = 0; kk < 32; ++kk) {
          const v8h af = *(const v8h*)(ap + kk * 32);
          const v8h bf = *(const v8h*)(bp + kk * 32);
          acc = __builtin_amdgcn_mfma_f32_16x16x32_f16(af, bf, acc, 0, 0, 0);
        }
      }
    } else {
      if (it >= 1) {                       // layer 1, t = it-1
        const int ww = w - 4, q = ww >> 1, s = ww & 1;
        if (s == 0) { acc[0] = bias1; acc[1] = bias1; acc[2] = bias1; acc[3] = bias1; }
        const _Float16* ap = hr + (q * 16 + lane16) * 2048 + s * 1024 + quad * 8;
        const _Float16* bp = &W1L[lane16][s * 1024 + quad * 8];
#pragma unroll 8
        for (int kk = 0; kk < 32; ++kk) {
          const v8h af = *(const v8h*)(ap + kk * 32);
          const v8h bf = *(const v8h*)(bp + kk * 32);
          acc = __builtin_amdgcn_mfma_f32_16x16x32_f16(af, bf, acc, 0, 0, 0);
        }
      }
    }

    // C-tile -> LDS scratch (C layout: row=quad*4+r, col=lane16)
#pragma unroll
    for (int r = 0; r < 4; ++r) zs[w][quad * 4 + r][lane16] = acc[r];
    __syncthreads();

    // elementwise: lane owns cell (b, u0+ej); gates at cols {ej,4+ej,8+ej,12+ej}
    const bool do0 = (w < 4) && (it < 512);
    const bool do1 = (w >= 4) && (((w - 4) & 1) == 0) && (it >= 1);
    if (do0 || do1) {
      float zi, zf, zg, zo;
      if (do0) {
        zi = zs[w][eb][ej];      zf = zs[w][eb][4 + ej];
        zg = zs[w][eb][8 + ej];  zo = zs[w][eb][12 + ej];
      } else {
        zi = zs[w][eb][ej] + zs[w + 1][eb][ej];
        zf = zs[w][eb][4 + ej] + zs[w + 1][eb][4 + ej];
        zg = zs[w][eb][8 + ej] + zs[w + 1][eb][8 + ej];
        zo = zs[w][eb][12 + ej] + zs[w + 1][eb][12 + ej];
      }
      const float ig = sigf(zi), fg = sigf(zf);
      const float gg = tanhf(zg), og = sigf(zo);
      cst = fg * cst + ig * gg;
      const float hv = og * tanhf(cst);
      if (do0) {
        const int b = w * 16 + eb;
        hw[b * 2048 + u0 + ej] = (_Float16)hv;            // h1_{it}
      } else {
        const int q = (w - 4) >> 1;
        const int b = q * 16 + eb;
        hw[b * 2048 + 1024 + u0 + ej] = (_Float16)hv;     // h2_{it-1}
        h2s[((it - 1) * 64 + b) * 1024 + u0 + ej] = (_Float16)hv;
      }
    }
    grid.sync();
  }
}

// ---------------------------------------------------------------- FC ----
// out[b][t][v] = sum_u h2s[t][b][u] * fc_w[v][u] + fc_b[v]
__global__ __launch_bounds__(256, 2) void fc_kernel(
    const _Float16* __restrict__ h2s, const float* __restrict__ fcwT,
    const float* __restrict__ fc_b, float* __restrict__ out) {
  __shared__ float hl[16][1024];      // 64 KB
  const int tid = threadIdx.x;
  const int t = blockIdx.x >> 2, bs = blockIdx.x & 3;
  const int v = tid & 127, hh = tid >> 7;

  const h2v* hp = (const h2v*)h2s;
  for (int idx = tid; idx < 8192; idx += 256) {
    const int bl = idx >> 9, kp = idx & 511;
    const h2v pr = hp[(t * 64 + bs * 16 + bl) * 512 + kp];
    hl[bl][2 * kp] = (float)pr.x;
    hl[bl][2 * kp + 1] = (float)pr.y;
  }
  __syncthreads();

  float acc[8];
#pragma unroll
  for (int i = 0; i < 8; ++i) acc[i] = 0.0f;
  const int bl0 = hh * 8;
#pragma unroll 1
  for (int k4 = 0; k4 < 256; ++k4) {
    const int k = k4 * 4;
    const float w0 = fcwT[(k + 0) * 128 + v];
    const float w1 = fcwT[(k + 1) * 128 + v];
    const float w2 = fcwT[(k + 2) * 128 + v];
    const float w3 = fcwT[(k + 3) * 128 + v];
#pragma unroll
    for (int i = 0; i < 8; ++i) {
      const float4 hv = *(const float4*)&hl[bl0 + i][k];
      acc[i] += hv.x * w0 + hv.y * w1 + hv.z * w2 + hv.w * w3;
    }
  }
  const float bias = fc_b[v];
#pragma unroll
  for (int i = 0; i < 8; ++i) {
    const int bb = bs * 16 + bl0 + i;
    out[(bb * 512 + t) * 128 + v] = acc[i] + bias;
  }
}

// ------------------------------------------------------------- launch ----
extern "C" void kernel_launch(void* const* d_in, const int* in_sizes, int n_in,
                              void* d_out, int out_size, void* d_ws,
                              size_t ws_size, hipStream_t stream) {
  const int* x = (const int*)d_in[0];
  const float* emb = (const float*)d_in[1];
  const float* w_ih0 = (const float*)d_in[2];
  const float* w_hh0 = (const float*)d_in[3];
  const float* b_ih0 = (const float*)d_in[4];
  const float* b_hh0 = (const float*)d_in[5];
  const float* w_ih1 = (const float*)d_in[6];
  const float* w_hh1 = (const float*)d_in[7];
  const float* b_ih1 = (const float*)d_in[8];
  const float* b_hh1 = (const float*)d_in[9];
  const float* fc_w = (const float*)d_in[10];
  const float* fc_b = (const float*)d_in[11];
  float* out = (float*)d_out;

  char* ws = (char*)d_ws;
  float* tableV = (float*)(ws);
  float* fcwT = (float*)(ws + 2097152);
  _Float16* hcat = (_Float16*)(ws + 2621440);
  _Float16* h2s = (_Float16*)(ws + 3145728);
  unsigned* zb = (unsigned*)(ws + 2621440);

  prep_kernel<<<2592, 256, 0, stream>>>(emb, w_ih0, b_ih0, b_hh0, fc_w,
                                        tableV, fcwT, zb);

  const float* tableVc = tableV;
  _Float16* hcata = hcat;
  _Float16* h2sa = h2s;
  void* args[] = {(void*)&x,     (void*)&tableVc, (void*)&w_hh0,
                  (void*)&w_ih1, (void*)&w_hh1,   (void*)&b_ih1,
                  (void*)&b_hh1, (void*)&hcata,   (void*)&h2sa};
  hipLaunchCooperativeKernel(lstm_mfma, dim3(256), dim3(768), args, 0, stream);

  fc_kernel<<<2048, 256, 0, stream>>>(h2s, fcwT, fc_b, out);
}

// Round 3
// 9511.841 us; speedup vs baseline: 5.6837x; 2.3366x over previous
//
#include <hip/hip_runtime.h>

// Shapes: VOCAB=128, EMBED=512, HIDDEN=1024, B=64, T=512. Inputs fp32, x int32.
// ws layout (bytes):
//   tableV : [128 vocab][4096 C] fp16   @ 0         (1 MB)   xin0+bias, block-local col order
//   fcwT   : [1024 k][128 v] fp32       @ 1048576   (512 KB)
//   hcat   : [2 bufs][64 b][2048 k] f16 @ 1572864   (512 KB) k<1024: h1, k>=1024: h2
//   h2s    : [512 t][64 b][1024 u] f16  @ 2097152   (64 MB)
//   cnt    : [513] u32 barrier counters @ 69206016  (2 KB)
//
// Column mapping: global col C = blk*16 + g*4 + j  <->  gate-row g*1024 + blk*4 + j.
//
// Cross-XCD protocol (replaces cg::grid.sync, which costs ~35 us/iter in L2
// flush+inv): all cross-block stores are agent-scope relaxed atomics
// (write-through sc0 sc1, never dirty in L2); barrier = vmcnt drain +
// atomicAdd + acquire-fence (buffer_inv of stale clean lines) + spin.
// h reads stay plain cached loads -> served from per-XCD L2 after first touch.

typedef _Float16 v8h __attribute__((ext_vector_type(8)));
typedef float v4f __attribute__((ext_vector_type(4)));
typedef _Float16 h2v __attribute__((ext_vector_type(2)));

__device__ __forceinline__ float sigf(float x) {
  return 1.0f / (1.0f + __expf(-x));
}

// ---------------------------------------------------------------- prep ----
__global__ __launch_bounds__(256) void prep_kernel(
    const float* __restrict__ emb, const float* __restrict__ w_ih0,
    const float* __restrict__ b_ih0, const float* __restrict__ b_hh0,
    const float* __restrict__ fc_w, _Float16* __restrict__ tableV,
    float* __restrict__ fcwT, unsigned* __restrict__ zbuf,
    unsigned* __restrict__ cnt) {
  const int blk = blockIdx.x, tid = threadIdx.x;
  if (blk < 2048) {
    // tableV[v][C] = emb[v]·w_ih0[row(C)] + b_ih0[row] + b_hh0[row]
    const int C = blk * 2 + (tid >> 7);
    const int v = tid & 127;
    const int row = ((C >> 2) & 3) * 1024 + (C >> 4) * 4 + (C & 3);
    float acc = b_ih0[row] + b_hh0[row];
    const float* er = emb + v * 512;
    const float* wr = w_ih0 + row * 512;
#pragma unroll 4
    for (int k = 0; k < 512; ++k) acc = fmaf(er[k], wr[k], acc);
    tableV[v * 4096 + C] = (_Float16)acc;
  } else if (blk < 2560) {
    const int idx = (blk - 2048) * 256 + tid;   // [0, 131072)
    const int v = idx & 127, k = idx >> 7;
    fcwT[k * 128 + v] = fc_w[v * 1024 + k];
  } else if (blk < 2592) {
    // zero hcat (both ping-pong buffers): 131072 dwords over 32 blocks
    const int idx = (blk - 2560) * 256 + tid;
#pragma unroll
    for (int q = 0; q < 16; ++q) zbuf[idx * 16 + q] = 0u;
  } else {
    for (int i = tid; i < 513; i += 256) cnt[i] = 0u;
  }
}

// ------------------------------------------------------------ recurrent ----
// 256 blocks x 768 threads (12 waves, 1 block/CU). Block owns units
// u0=4*blk..u0+3 (16 gate-cols per layer). Weights LDS-resident fp16 in
// B-fragment layout [col][k] (+8 halfs pad). Skew: iteration it does layer0
// step t=it (waves 0-3) and layer1 step t=it-1 (waves 4-11, LDS-reduced).
__global__ __launch_bounds__(768, 1) void lstm_mfma(
    const int* __restrict__ x, const _Float16* __restrict__ tableV,
    const float* __restrict__ w_hh0, const float* __restrict__ w_ih1,
    const float* __restrict__ w_hh1, const float* __restrict__ b_ih1,
    const float* __restrict__ b_hh1, _Float16* __restrict__ hcat,
    _Float16* __restrict__ h2s, unsigned* __restrict__ cnt) {
  __shared__ _Float16 W0L[16][1024 + 8];   // 33 KB
  __shared__ _Float16 W1L[16][2048 + 8];   // 66 KB (k<1024: w_ih1, else w_hh1)
  __shared__ float zs[12][16][17];         // per-wave C-tile scratch, 13 KB

  const int tid = threadIdx.x, blk = blockIdx.x;
  const int w = tid >> 6, l = tid & 63;
  const int lane16 = l & 15, quad = l >> 4;
  const int u0 = blk * 4;

  // --- stage weights (once): fp32 global -> fp16 LDS ---
  for (int e = tid; e < 16 * 1024; e += 768) {
    const int n = e >> 10, k = e & 1023;
    const int row = (n >> 2) * 1024 + u0 + (n & 3);
    W0L[n][k] = (_Float16)w_hh0[row * 1024 + k];
  }
  for (int e = tid; e < 16 * 2048; e += 768) {
    const int n = e >> 11, k = e & 2047;
    const int row = (n >> 2) * 1024 + u0 + (n & 3);
    const float src = (k < 1024) ? w_ih1[row * 1024 + k]
                                 : w_hh1[row * 1024 + (k - 1024)];
    W1L[n][k] = (_Float16)src;
  }

  float bias1 = 0.0f;
  if (w >= 4 && ((w - 4) & 1) == 0) {
    const int row = (lane16 >> 2) * 1024 + u0 + (lane16 & 3);
    bias1 = b_ih1[row] + b_hh1[row];
  }
  __syncthreads();

  float cst = 0.0f;                        // cell state (per owner lane)
  const int eb = l >> 2, ej = l & 3;       // elementwise cell mapping

  for (int it = 0; it <= 512; ++it) {
    const _Float16* hr = hcat + (it & 1) * 131072;      // [64][2048]
    _Float16* hw = hcat + ((it + 1) & 1) * 131072;

    v4f acc = {0.0f, 0.0f, 0.0f, 0.0f};
    _Float16 tv[4];
    if (w < 4) {
      if (it < 512) {                      // layer 0, t = it
        // issue the xin0 gather early; fold in AFTER the MFMA chain so the
        // loads overlap the matmul instead of gating it
#pragma unroll
        for (int r = 0; r < 4; ++r) {
          const int b = w * 16 + quad * 4 + r;
          const int xv = x[b * 512 + it];
          tv[r] = tableV[xv * 4096 + blk * 16 + lane16];
        }
        const _Float16* ap = hr + (w * 16 + lane16) * 2048 + quad * 8;
        const _Float16* bp = &W0L[lane16][quad * 8];
#pragma unroll 8
        for (int kk = 0; kk < 32; ++kk) {
          const v8h af = *(const v8h*)(ap + kk * 32);
          const v8h bf = *(const v8h*)(bp + kk * 32);
          acc = __builtin_amdgcn_mfma_f32_16x16x32_f16(af, bf, acc, 0, 0, 0);
        }
#pragma unroll
        for (int r = 0; r < 4; ++r) acc[r] += (float)tv[r];
      }
    } else {
      if (it >= 1) {                       // layer 1, t = it-1
        const int ww = w - 4, q = ww >> 1, s = ww & 1;
        if (s == 0) { acc[0] = bias1; acc[1] = bias1; acc[2] = bias1; acc[3] = bias1; }
        const _Float16* ap = hr + (q * 16 + lane16) * 2048 + s * 1024 + quad * 8;
        const _Float16* bp = &W1L[lane16][s * 1024 + quad * 8];
#pragma unroll 8
        for (int kk = 0; kk < 32; ++kk) {
          const v8h af = *(const v8h*)(ap + kk * 32);
          const v8h bf = *(const v8h*)(bp + kk * 32);
          acc = __builtin_amdgcn_mfma_f32_16x16x32_f16(af, bf, acc, 0, 0, 0);
        }
      }
    }

    // C-tile -> LDS scratch (C layout: row=quad*4+r, col=lane16)
#pragma unroll
    for (int r = 0; r < 4; ++r) zs[w][quad * 4 + r][lane16] = acc[r];
    __syncthreads();

    // elementwise: lane owns cell (b, u0+ej); gates at cols {ej,4+ej,8+ej,12+ej}
    const bool do0 = (w < 4) && (it < 512);
    const bool do1 = (w >= 4) && (((w - 4) & 1) == 0) && (it >= 1);
    if (do0 || do1) {
      float zi, zf, zg, zo;
      if (do0) {
        zi = zs[w][eb][ej];      zf = zs[w][eb][4 + ej];
        zg = zs[w][eb][8 + ej];  zo = zs[w][eb][12 + ej];
      } else {
        zi = zs[w][eb][ej] + zs[w + 1][eb][ej];
        zf = zs[w][eb][4 + ej] + zs[w + 1][eb][4 + ej];
        zg = zs[w][eb][8 + ej] + zs[w + 1][eb][8 + ej];
        zo = zs[w][eb][12 + ej] + zs[w + 1][eb][12 + ej];
      }
      const float ig = sigf(zi), fg = sigf(zf);
      const float gg = tanhf(zg), og = sigf(zo);
      cst = fg * cst + ig * gg;
      const float hv = og * tanhf(cst);

      // pack 4 units' h (consecutive lanes ej=0..3) into one 8-B coherent store
      const unsigned hu = (unsigned)__builtin_bit_cast(unsigned short, (_Float16)hv);
      const unsigned p1 = (unsigned)__shfl_xor((int)hu, 1, 64);
      const unsigned lo = (ej & 1) ? ((p1 & 0xffffu) | (hu << 16))
                                   : ((hu & 0xffffu) | (p1 << 16));
      const unsigned p2 = (unsigned)__shfl_xor((int)lo, 2, 64);
      if (ej == 0) {
        const unsigned long long val =
            (unsigned long long)lo | ((unsigned long long)p2 << 32);
        if (do0) {
          const int b = w * 16 + eb;
          __hip_atomic_store((unsigned long long*)(hw + b * 2048 + u0), val,
                             __ATOMIC_RELAXED, __HIP_MEMORY_SCOPE_AGENT);
        } else {
          const int q = (w - 4) >> 1;
          const int b = q * 16 + eb;
          __hip_atomic_store(
              (unsigned long long*)(hw + b * 2048 + 1024 + u0), val,
              __ATOMIC_RELAXED, __HIP_MEMORY_SCOPE_AGENT);
          __hip_atomic_store(
              (unsigned long long*)(h2s + ((it - 1) * 64 + b) * 1024 + u0),
              val, __ATOMIC_RELAXED, __HIP_MEMORY_SCOPE_AGENT);
        }
      }
    }

    if (it < 512) {
      // ---- custom multi-XCD barrier (no L2 flush) ----
      asm volatile("s_waitcnt vmcnt(0)" ::: "memory");  // our stores at L3
      __syncthreads();                                   // whole block done
      if (tid == 0) {
        __hip_atomic_fetch_add(cnt + it, 1u, __ATOMIC_RELAXED,
                               __HIP_MEMORY_SCOPE_AGENT);
        // drop stale clean L1/L2 lines now; consumers' post-barrier fills
        // happen later and are not wiped. Nothing dirty exists (all shared
        // stores are write-through), so invalidate loses nothing.
        __builtin_amdgcn_fence(__ATOMIC_ACQUIRE, "agent");
        while (__hip_atomic_load(cnt + it, __ATOMIC_RELAXED,
                                 __HIP_MEMORY_SCOPE_AGENT) < 256u)
          __builtin_amdgcn_s_sleep(2);
      }
      __syncthreads();
    }
  }
}

// ---------------------------------------------------------------- FC ----
__global__ __launch_bounds__(256, 2) void fc_kernel(
    const _Float16* __restrict__ h2s, const float* __restrict__ fcwT,
    const float* __restrict__ fc_b, float* __restrict__ out) {
  __shared__ float hl[16][1024];      // 64 KB
  const int tid = threadIdx.x;
  const int t = blockIdx.x >> 2, bs = blockIdx.x & 3;
  const int v = tid & 127, hh = tid >> 7;

  const h2v* hp = (const h2v*)h2s;
  for (int idx = tid; idx < 8192; idx += 256) {
    const int bl = idx >> 9, kp = idx & 511;
    const h2v pr = hp[(t * 64 + bs * 16 + bl) * 512 + kp];
    hl[bl][2 * kp] = (float)pr.x;
    hl[bl][2 * kp + 1] = (float)pr.y;
  }
  __syncthreads();

  float acc[8];
#pragma unroll
  for (int i = 0; i < 8; ++i) acc[i] = 0.0f;
  const int bl0 = hh * 8;
#pragma unroll 1
  for (int k4 = 0; k4 < 256; ++k4) {
    const int k = k4 * 4;
    const float w0 = fcwT[(k + 0) * 128 + v];
    const float w1 = fcwT[(k + 1) * 128 + v];
    const float w2 = fcwT[(k + 2) * 128 + v];
    const float w3 = fcwT[(k + 3) * 128 + v];
#pragma unroll
    for (int i = 0; i < 8; ++i) {
      const float4 hv = *(const float4*)&hl[bl0 + i][k];
      acc[i] += hv.x * w0 + hv.y * w1 + hv.z * w2 + hv.w * w3;
    }
  }
  const float bias = fc_b[v];
#pragma unroll
  for (int i = 0; i < 8; ++i) {
    const int bb = bs * 16 + bl0 + i;
    out[(bb * 512 + t) * 128 + v] = acc[i] + bias;
  }
}

// ------------------------------------------------------------- launch ----
extern "C" void kernel_launch(void* const* d_in, const int* in_sizes, int n_in,
                              void* d_out, int out_size, void* d_ws,
                              size_t ws_size, hipStream_t stream) {
  const int* x = (const int*)d_in[0];
  const float* emb = (const float*)d_in[1];
  const float* w_ih0 = (const float*)d_in[2];
  const float* w_hh0 = (const float*)d_in[3];
  const float* b_ih0 = (const float*)d_in[4];
  const float* b_hh0 = (const float*)d_in[5];
  const float* w_ih1 = (const float*)d_in[6];
  const float* w_hh1 = (const float*)d_in[7];
  const float* b_ih1 = (const float*)d_in[8];
  const float* b_hh1 = (const float*)d_in[9];
  const float* fc_w = (const float*)d_in[10];
  const float* fc_b = (const float*)d_in[11];
  float* out = (float*)d_out;

  char* ws = (char*)d_ws;
  _Float16* tableV = (_Float16*)(ws);
  float* fcwT = (float*)(ws + 1048576);
  _Float16* hcat = (_Float16*)(ws + 1572864);
  _Float16* h2s = (_Float16*)(ws + 2097152);
  unsigned* cnt = (unsigned*)(ws + 69206016);
  unsigned* zb = (unsigned*)(ws + 1572864);

  prep_kernel<<<2593, 256, 0, stream>>>(emb, w_ih0, b_ih0, b_hh0, fc_w,
                                        tableV, fcwT, zb, cnt);

  const _Float16* tableVc = tableV;
  _Float16* hcata = hcat;
  _Float16* h2sa = h2s;
  unsigned* cnta = cnt;
  void* args[] = {(void*)&x,     (void*)&tableVc, (void*)&w_hh0,
                  (void*)&w_ih1, (void*)&w_hh1,   (void*)&b_ih1,
                  (void*)&b_hh1, (void*)&hcata,   (void*)&h2sa,
                  (void*)&cnta};
  hipLaunchCooperativeKernel(lstm_mfma, dim3(256), dim3(768), args, 0, stream);

  fc_kernel<<<2048, 256, 0, stream>>>(h2s, fcwT, fc_b, out);
}

// Round 4
// 8735.946 us; speedup vs baseline: 6.1885x; 1.0888x over previous
//
#include <hip/hip_runtime.h>

// Shapes: VOCAB=128, EMBED=512, HIDDEN=1024, B=64, T=512. Inputs fp32, x int32.
// ws layout (bytes):
//   tableV : [128 vocab][4096 C] fp16   @ 0         (1 MB)   xin0+bias, block-local col order
//   fcwT   : [1024 k][128 v] fp16       @ 1048576   (256 KB)
//   hcat   : [2 bufs][64 b][2048 k] f16 @ 1310720   (512 KB) k<1024: h1, k>=1024: h2
//   cnt    : [512 it][112 words] u32    @ 1835008   (224 KB) hierarchical barrier
//   h2s    : [512 t][64 b][1024 u] f16  @ 2064384   (64 MB)  total 69,173,248 B
//
// Column mapping: global col C = blk*16 + g*4 + j  <->  gate-row g*1024 + blk*4 + j.
//
// Cross-XCD protocol: all cross-block stores are agent-scope relaxed atomics
// (write-through, never dirty in L2); barrier = vmcnt drain + HIERARCHICAL
// arrive (8 group counters x 32 blocks -> root x 8 -> 8 release flags) +
// acquire-fence (inv stale clean L1/L2) + spin on group flag. Flat 256-deep
// same-address atomic chain (~14 us/iter in round 3) becomes 32-deep.
// Barrier words per iter (112): arrive[g]@g*8, root@72, release[g]@80+g*4.

typedef _Float16 v8h __attribute__((ext_vector_type(8)));
typedef float v4f __attribute__((ext_vector_type(4)));
typedef _Float16 h2v __attribute__((ext_vector_type(2)));

__device__ __forceinline__ float sigf(float x) {
  return 1.0f / (1.0f + __expf(-x));
}

// ---------------------------------------------------------------- prep ----
__global__ __launch_bounds__(256) void prep_kernel(
    const float* __restrict__ emb, const float* __restrict__ w_ih0,
    const float* __restrict__ b_ih0, const float* __restrict__ b_hh0,
    const float* __restrict__ fc_w, _Float16* __restrict__ tableV,
    _Float16* __restrict__ fcwT, unsigned* __restrict__ zbuf,
    unsigned* __restrict__ cnt) {
  const int blk = blockIdx.x, tid = threadIdx.x;
  if (blk < 2048) {
    // tableV[v][C] = emb[v]·w_ih0[row(C)] + b_ih0[row] + b_hh0[row]
    const int C = blk * 2 + (tid >> 7);
    const int v = tid & 127;
    const int row = ((C >> 2) & 3) * 1024 + (C >> 4) * 4 + (C & 3);
    float acc = b_ih0[row] + b_hh0[row];
    const float* er = emb + v * 512;
    const float* wr = w_ih0 + row * 512;
#pragma unroll 4
    for (int k = 0; k < 512; ++k) acc = fmaf(er[k], wr[k], acc);
    tableV[v * 4096 + C] = (_Float16)acc;
  } else if (blk < 2560) {
    const int idx = (blk - 2048) * 256 + tid;   // [0, 131072)
    const int v = idx & 127, k = idx >> 7;
    fcwT[k * 128 + v] = (_Float16)fc_w[v * 1024 + k];
  } else if (blk < 2592) {
    // zero hcat (both ping-pong buffers): 131072 dwords over 32 blocks
    const int idx = (blk - 2560) * 256 + tid;
#pragma unroll
    for (int q = 0; q < 16; ++q) zbuf[idx * 16 + q] = 0u;
  } else {
    // zero barrier counters: 512*112 = 57344 words over 32 blocks
    const int base = (blk - 2592) * 256 + tid;
    for (int i = base; i < 57344; i += 8192) cnt[i] = 0u;
  }
}

// ------------------------------------------------------------ recurrent ----
// 256 blocks x 768 threads (12 waves, 1 block/CU). Block owns units
// u0=4*blk..u0+3 (16 gate-cols per layer). Weights LDS-resident fp16 in
// B-fragment layout [col][k] (+8 halfs pad). Skew: iteration it does layer0
// step t=it (waves 0-3) and layer1 step t=it-1 (waves 4-11, LDS-reduced).
__global__ __launch_bounds__(768, 1) void lstm_mfma(
    const int* __restrict__ x, const _Float16* __restrict__ tableV,
    const float* __restrict__ w_hh0, const float* __restrict__ w_ih1,
    const float* __restrict__ w_hh1, const float* __restrict__ b_ih1,
    const float* __restrict__ b_hh1, _Float16* __restrict__ hcat,
    _Float16* __restrict__ h2s, unsigned* __restrict__ cnt) {
  __shared__ _Float16 W0L[16][1024 + 8];   // 33 KB
  __shared__ _Float16 W1L[16][2048 + 8];   // 66 KB (k<1024: w_ih1, else w_hh1)
  __shared__ float zs[12][16][17];         // per-wave C-tile scratch, 13 KB

  const int tid = threadIdx.x, blk = blockIdx.x;
  const int w = tid >> 6, l = tid & 63;
  const int lane16 = l & 15, quad = l >> 4;
  const int u0 = blk * 4;

  // --- stage weights (once): fp32 global -> fp16 LDS ---
  for (int e = tid; e < 16 * 1024; e += 768) {
    const int n = e >> 10, k = e & 1023;
    const int row = (n >> 2) * 1024 + u0 + (n & 3);
    W0L[n][k] = (_Float16)w_hh0[row * 1024 + k];
  }
  for (int e = tid; e < 16 * 2048; e += 768) {
    const int n = e >> 11, k = e & 2047;
    const int row = (n >> 2) * 1024 + u0 + (n & 3);
    const float src = (k < 1024) ? w_ih1[row * 1024 + k]
                                 : w_hh1[row * 1024 + (k - 1024)];
    W1L[n][k] = (_Float16)src;
  }

  float bias1 = 0.0f;
  if (w >= 4 && ((w - 4) & 1) == 0) {
    const int row = (lane16 >> 2) * 1024 + u0 + (lane16 & 3);
    bias1 = b_ih1[row] + b_hh1[row];
  }
  __syncthreads();

  float cst = 0.0f;                        // cell state (per owner lane)
  const int eb = l >> 2, ej = l & 3;       // elementwise cell mapping

  // prefetch iteration-0 xin0 gather (tableV is constant -> safe to hoist)
  _Float16 tv[4];
  if (w < 4) {
#pragma unroll
    for (int r = 0; r < 4; ++r) {
      const int b = w * 16 + quad * 4 + r;
      tv[r] = tableV[x[b * 512] * 4096 + blk * 16 + lane16];
    }
  }

  for (int it = 0; it <= 512; ++it) {
    const _Float16* hr = hcat + (it & 1) * 131072;      // [64][2048]
    _Float16* hw = hcat + ((it + 1) & 1) * 131072;

    v4f acc = {0.0f, 0.0f, 0.0f, 0.0f};
    if (w < 4) {
      if (it < 512) {                      // layer 0, t = it
        const _Float16* ap = hr + (w * 16 + lane16) * 2048 + quad * 8;
        const _Float16* bp = &W0L[lane16][quad * 8];
#pragma unroll 8
        for (int kk = 0; kk < 32; ++kk) {
          const v8h af = *(const v8h*)(ap + kk * 32);
          const v8h bf = *(const v8h*)(bp + kk * 32);
          acc = __builtin_amdgcn_mfma_f32_16x16x32_f16(af, bf, acc, 0, 0, 0);
        }
#pragma unroll
        for (int r = 0; r < 4; ++r) acc[r] += (float)tv[r];
      }
    } else {
      if (it >= 1) {                       // layer 1, t = it-1
        const int ww = w - 4, q = ww >> 1, s = ww & 1;
        if (s == 0) { acc[0] = bias1; acc[1] = bias1; acc[2] = bias1; acc[3] = bias1; }
        const _Float16* ap = hr + (q * 16 + lane16) * 2048 + s * 1024 + quad * 8;
        const _Float16* bp = &W1L[lane16][s * 1024 + quad * 8];
#pragma unroll 8
        for (int kk = 0; kk < 32; ++kk) {
          const v8h af = *(const v8h*)(ap + kk * 32);
          const v8h bf = *(const v8h*)(bp + kk * 32);
          acc = __builtin_amdgcn_mfma_f32_16x16x32_f16(af, bf, acc, 0, 0, 0);
        }
      }
    }

    // C-tile -> LDS scratch (C layout: row=quad*4+r, col=lane16)
#pragma unroll
    for (int r = 0; r < 4; ++r) zs[w][quad * 4 + r][lane16] = acc[r];
    __syncthreads();

    // elementwise: lane owns cell (b, u0+ej); gates at cols {ej,4+ej,8+ej,12+ej}
    const bool do0 = (w < 4) && (it < 512);
    const bool do1 = (w >= 4) && (((w - 4) & 1) == 0) && (it >= 1);
    if (do0 || do1) {
      float zi, zf, zg, zo;
      if (do0) {
        zi = zs[w][eb][ej];      zf = zs[w][eb][4 + ej];
        zg = zs[w][eb][8 + ej];  zo = zs[w][eb][12 + ej];
      } else {
        zi = zs[w][eb][ej] + zs[w + 1][eb][ej];
        zf = zs[w][eb][4 + ej] + zs[w + 1][eb][4 + ej];
        zg = zs[w][eb][8 + ej] + zs[w + 1][eb][8 + ej];
        zo = zs[w][eb][12 + ej] + zs[w + 1][eb][12 + ej];
      }
      const float ig = sigf(zi), fg = sigf(zf);
      const float gg = tanhf(zg), og = sigf(zo);
      cst = fg * cst + ig * gg;
      const float hv = og * tanhf(cst);

      // pack 4 units' h (consecutive lanes ej=0..3) into one 8-B coherent store
      const unsigned hu = (unsigned)__builtin_bit_cast(unsigned short, (_Float16)hv);
      const unsigned p1 = (unsigned)__shfl_xor((int)hu, 1, 64);
      const unsigned lo = (ej & 1) ? ((p1 & 0xffffu) | (hu << 16))
                                   : ((hu & 0xffffu) | (p1 << 16));
      const unsigned p2 = (unsigned)__shfl_xor((int)lo, 2, 64);
      if (ej == 0) {
        const unsigned long long val =
            (unsigned long long)lo | ((unsigned long long)p2 << 32);
        if (do0) {
          const int b = w * 16 + eb;
          __hip_atomic_store((unsigned long long*)(hw + b * 2048 + u0), val,
                             __ATOMIC_RELAXED, __HIP_MEMORY_SCOPE_AGENT);
        } else {
          const int q = (w - 4) >> 1;
          const int b = q * 16 + eb;
          __hip_atomic_store(
              (unsigned long long*)(hw + b * 2048 + 1024 + u0), val,
              __ATOMIC_RELAXED, __HIP_MEMORY_SCOPE_AGENT);
          __hip_atomic_store(
              (unsigned long long*)(h2s + ((it - 1) * 64 + b) * 1024 + u0),
              val, __ATOMIC_RELAXED, __HIP_MEMORY_SCOPE_AGENT);
        }
      }
    }

    // prefetch next iteration's xin0 gather before the barrier (overlaps it)
    if (w < 4 && it + 1 < 512) {
#pragma unroll
      for (int r = 0; r < 4; ++r) {
        const int b = w * 16 + quad * 4 + r;
        tv[r] = tableV[x[b * 512 + it + 1] * 4096 + blk * 16 + lane16];
      }
    }

    if (it < 512) {
      // ---- hierarchical multi-XCD barrier (no L2 flush, low contention) ----
      unsigned* base = cnt + it * 112;
      asm volatile("s_waitcnt vmcnt(0)" ::: "memory");  // stores + prefetch done
      __syncthreads();                                   // whole block done
      if (tid == 0) {
        const int g = blk & 7;
        const unsigned old = __hip_atomic_fetch_add(
            base + g * 8, 1u, __ATOMIC_RELAXED, __HIP_MEMORY_SCOPE_AGENT);
        // drop stale clean L1/L2 lines now; post-release refills are fresh.
        __builtin_amdgcn_fence(__ATOMIC_ACQUIRE, "agent");
        if (old == 31u) {                 // last of this group
          const unsigned r = __hip_atomic_fetch_add(
              base + 72, 1u, __ATOMIC_RELAXED, __HIP_MEMORY_SCOPE_AGENT);
          if (r == 7u) {                  // last group overall -> release all
#pragma unroll
            for (int xx = 0; xx < 8; ++xx)
              __hip_atomic_store(base + 80 + xx * 4, 1u, __ATOMIC_RELAXED,
                                 __HIP_MEMORY_SCOPE_AGENT);
          }
        }
        while (__hip_atomic_load(base + 80 + g * 4, __ATOMIC_RELAXED,
                                 __HIP_MEMORY_SCOPE_AGENT) == 0u) {}
      }
      __syncthreads();
    }
  }
}

// ---------------------------------------------------------------- FC ----
__global__ __launch_bounds__(256, 2) void fc_kernel(
    const _Float16* __restrict__ h2s, const _Float16* __restrict__ fcwT,
    const float* __restrict__ fc_b, float* __restrict__ out) {
  __shared__ float hl[16][1024];      // 64 KB
  const int tid = threadIdx.x;
  const int t = blockIdx.x >> 2, bs = blockIdx.x & 3;
  const int v = tid & 127, hh = tid >> 7;

  const h2v* hp = (const h2v*)h2s;
  for (int idx = tid; idx < 8192; idx += 256) {
    const int bl = idx >> 9, kp = idx & 511;
    const h2v pr = hp[(t * 64 + bs * 16 + bl) * 512 + kp];
    hl[bl][2 * kp] = (float)pr.x;
    hl[bl][2 * kp + 1] = (float)pr.y;
  }
  __syncthreads();

  float acc[8];
#pragma unroll
  for (int i = 0; i < 8; ++i) acc[i] = 0.0f;
  const int bl0 = hh * 8;
#pragma unroll 1
  for (int k4 = 0; k4 < 256; ++k4) {
    const int k = k4 * 4;
    const float w0 = (float)fcwT[(k + 0) * 128 + v];
    const float w1 = (float)fcwT[(k + 1) * 128 + v];
    const float w2 = (float)fcwT[(k + 2) * 128 + v];
    const float w3 = (float)fcwT[(k + 3) * 128 + v];
#pragma unroll
    for (int i = 0; i < 8; ++i) {
      const float4 hv = *(const float4*)&hl[bl0 + i][k];
      acc[i] += hv.x * w0 + hv.y * w1 + hv.z * w2 + hv.w * w3;
    }
  }
  const float bias = fc_b[v];
#pragma unroll
  for (int i = 0; i < 8; ++i) {
    const int bb = bs * 16 + bl0 + i;
    out[(bb * 512 + t) * 128 + v] = acc[i] + bias;
  }
}

// ------------------------------------------------------------- launch ----
extern "C" void kernel_launch(void* const* d_in, const int* in_sizes, int n_in,
                              void* d_out, int out_size, void* d_ws,
                              size_t ws_size, hipStream_t stream) {
  const int* x = (const int*)d_in[0];
  const float* emb = (const float*)d_in[1];
  const float* w_ih0 = (const float*)d_in[2];
  const float* w_hh0 = (const float*)d_in[3];
  const float* b_ih0 = (const float*)d_in[4];
  const float* b_hh0 = (const float*)d_in[5];
  const float* w_ih1 = (const float*)d_in[6];
  const float* w_hh1 = (const float*)d_in[7];
  const float* b_ih1 = (const float*)d_in[8];
  const float* b_hh1 = (const float*)d_in[9];
  const float* fc_w = (const float*)d_in[10];
  const float* fc_b = (const float*)d_in[11];
  float* out = (float*)d_out;

  char* ws = (char*)d_ws;
  _Float16* tableV = (_Float16*)(ws);
  _Float16* fcwT = (_Float16*)(ws + 1048576);
  _Float16* hcat = (_Float16*)(ws + 1310720);
  unsigned* cnt = (unsigned*)(ws + 1835008);
  _Float16* h2s = (_Float16*)(ws + 2064384);
  unsigned* zb = (unsigned*)(ws + 1310720);

  prep_kernel<<<2624, 256, 0, stream>>>(emb, w_ih0, b_ih0, b_hh0, fc_w,
                                        tableV, fcwT, zb, cnt);

  const _Float16* tableVc = tableV;
  _Float16* hcata = hcat;
  _Float16* h2sa = h2s;
  unsigned* cnta = cnt;
  void* args[] = {(void*)&x,     (void*)&tableVc, (void*)&w_hh0,
                  (void*)&w_ih1, (void*)&w_hh1,   (void*)&b_ih1,
                  (void*)&b_hh1, (void*)&hcata,   (void*)&h2sa,
                  (void*)&cnta};
  hipLaunchCooperativeKernel(lstm_mfma, dim3(256), dim3(768), args, 0, stream);

  fc_kernel<<<2048, 256, 0, stream>>>(h2s, fcwT, fc_b, out);
}